// Round 3
// baseline (89.057 us; speedup 1.0000x reference)
//
#include <hip/hip_runtime.h>
#include <float.h>

#define FH 64
#define FW 64
#define FC 256
#define NB 4
#define NR 128
#define NREG 32
#define POOLH 3
#define POOLW 3
#define IOU_THR 0.4f
#define NCELL (POOLH * POOLW)

#define POOLED_ELEMS (NB * NREG * NCELL * FC)

// Python floor-division semantics for /2 on possibly-negative ints:
// arithmetic shift right == floor division by 2 on two's complement.
__device__ inline void fix_axis(int mn, int mx, int ps, int fs, int& omin, int& omax) {
    int pad = ps - (mx - mn);
    bool fix_min = mn < (pad >> 1);
    bool fix_max = (fs - mx) < ((1 + pad) >> 1);
    bool sym = (pad > 0) && !(fix_min || fix_max);
    omin = sym ? (mn - (pad >> 1)) : mn;
    omax = sym ? (mx + ((1 + pad) >> 1)) : mx;
    if ((pad > 0) && fix_min) { omin = 0; omax = ps; }
    if ((pad > 0) && fix_max) { omin = fs - ps; omax = fs; }
}

__device__ inline float4 max4(float4 a, float4 b) {
    float4 o;
    o.x = fmaxf(a.x, b.x); o.y = fmaxf(a.y, b.y);
    o.z = fmaxf(a.z, b.z); o.w = fmaxf(a.w, b.w);
    return o;
}

// Broadcast lane `lane`'s 64-bit value to all lanes of the wave (lane uniform).
__device__ inline unsigned long long readlane64(unsigned long long v, int lane) {
    unsigned lo = (unsigned)__builtin_amdgcn_readlane((int)(unsigned)v, lane);
    unsigned hi = (unsigned)__builtin_amdgcn_readlane((int)(unsigned)(v >> 32), lane);
    return ((unsigned long long)hi << 32) | lo;
}

// One block per (region, pool-cell). Redundant bitmask NMS per block, resolve
// via kept-bit scan on wave 0 with register-held rows (readlane fetch), then
// float4 pooling with in-register offsets (magic div) and 8 loads in flight.
__global__ __launch_bounds__(256) void fused_kernel(
    const float* __restrict__ features,  // (B, H, W, C)
    const float* __restrict__ roi,       // (B, R, 4)
    float* __restrict__ out)             // pooled (B,32,3,3,C) ++ roi_clipped (B,32,4)
{
    // XCD batch-affinity swizzle: consecutive hw block IDs round-robin the 8
    // XCDs (id & 7). Put batch b's 288 blocks on XCD pair {2b, 2b+1} so its
    // 4 MB feature slab stays resident in 8 MB of paired L2.
    const int hwid = blockIdx.x;
    const int b = (hwid >> 1) & 3;
    const int j = (hwid >> 3) * 2 + (hwid & 1);   // 0..287 within batch
    const int r = j / NCELL;                      // region 0..31
    const int cell = j - r * NCELL;               // 0..8
    const int ci = cell / POOLW, cj = cell - ci * POOLW;
    const int reg = b * NREG + r;
    const int tid = threadIdx.x;
    const int group = tid >> 6;                   // 0..3
    const int lane = tid & 63;

    __shared__ float sx1[NR], sy1[NR], sx2[NR], sy2[NR], sarea[NR];
    __shared__ unsigned long long smask[NR][2];
    __shared__ int sbox[4];
    __shared__ float4 sred[4][64];

    // Load this batch's boxes
    if (tid < NR) {
        const float4 bx = *(const float4*)(roi + ((size_t)b * NR + tid) * 4);
        sx1[tid] = bx.x; sy1[tid] = bx.y;
        sx2[tid] = bx.x + bx.z; sy2[tid] = bx.y + bx.w;
        sarea[tid] = bx.z * bx.w;
    }
    __syncthreads();

    // Row-build: p = tid&127 owns row p; half = tid>>7 covers 64 j's.
    // Division-free IoU: inter/(A+B-inter) > t <=> inter > t*(A+B-inter).
    {
        const int p = tid & 127;
        const int half = tid >> 7;
        const int j0 = half << 6;
        const float px1 = sx1[p], py1 = sy1[p], px2 = sx2[p], py2 = sy2[p], pa = sarea[p];
        unsigned long long m = 0ull;
        #pragma unroll 8
        for (int t = 0; t < 64; ++t) {
            const int jj = j0 + t;
            float iw = fmaxf(fminf(px2, sx2[jj]) - fmaxf(px1, sx1[jj]), 0.0f);
            float ih = fmaxf(fminf(py2, sy2[jj]) - fmaxf(py1, sy1[jj]), 0.0f);
            float inter = iw * ih;
            bool sup = (jj > p) && (inter > IOU_THR * (pa + sarea[jj] - inter));
            m |= ((unsigned long long)sup) << t;
        }
        smask[p][half] = m;
    }
    __syncthreads();

    // Resolve on wave 0: scan kept bits (a box still set when reached is
    // final-kept -> enumerate kept in ascending order, stop at 32). Rows are
    // held in wave-0 registers; fetch by readlane (no LDS latency).
    if (tid < 64) {
        const unsigned long long aLo = smask[tid][0];       // row tid, bits [0,64)
        const unsigned long long aHi = smask[tid][1];       // row tid, bits [64,128)
        const unsigned long long bHi = smask[tid + 64][1];  // row tid+64 (low half is 0)

        unsigned long long k1 = ~0ull;   // half-1 survivors under half-0 kept rows
        int cnt = 0, idx = NR - 1;

        unsigned long long cur = ~0ull;  // half-0 candidates
        while (cur && cnt < NREG) {
            int p = __ffsll((unsigned long long)cur) - 1;
            if (cnt == r) idx = p;
            ++cnt;
            int ps = __builtin_amdgcn_readfirstlane(p);
            unsigned long long m0 = readlane64(aLo, ps);
            unsigned long long m1 = readlane64(aHi, ps);
            cur = (cur & (cur - 1)) & ~m0;   // drop p + its suppressions
            k1 &= ~m1;
        }
        cur = k1;
        while (cur && cnt < NREG) {
            int p = __ffsll((unsigned long long)cur) - 1;
            if (cnt == r) idx = 64 + p;
            ++cnt;
            int ps = __builtin_amdgcn_readfirstlane(p);
            unsigned long long m1 = readlane64(bHi, ps);
            cur = (cur & (cur - 1)) & ~m1;
        }

        if (tid == 0) {
            // Clip from LDS: sx2 = x1+w exactly matches reference x+w.
            float x1 = sx1[idx], y1 = sy1[idx], x2f = sx2[idx], y2f = sy2[idx];
            int x_min = (int)fmaxf(0.0f, x1);
            int y_min = (int)fmaxf(0.0f, y1);
            int x_max = (int)fminf((float)FW, x2f);
            int y_max = (int)fminf((float)FH, y2f);
            int xmn, xmx, ymn, ymx;
            fix_axis(x_min, x_max, POOLW, FW, xmn, xmx);
            fix_axis(y_min, y_max, POOLH, FH, ymn, ymx);
            sbox[0] = xmn; sbox[1] = ymn; sbox[2] = xmx - xmn; sbox[3] = ymx - ymn;
            if (cell == 0) {
                float* orc = out + POOLED_ELEMS + ((size_t)reg) * 4;
                orc[0] = (float)xmn;
                orc[1] = (float)ymn;
                orc[2] = (float)(xmx - xmn);
                orc[3] = (float)(ymx - ymn);
            }
        }
    }
    __syncthreads();

    // Cell bounds + in-register offset math (no spix LDS, no extra barrier).
    const int x = sbox[0], y = sbox[1], w = sbox[2], h = sbox[3];
    const int hh = h / POOLH;
    const int ww = w / POOLW;
    const int r0 = y + ci * hh;
    const int r1 = (ci < POOLH - 1) ? (y + (ci + 1) * hh) : (y + h);
    const int c0 = x + cj * ww;
    const int c1 = (cj < POOLW - 1) ? (x + (cj + 1) * ww) : (x + w);
    const int ncols = c1 - c0;                    // 1..12
    const int n = (r1 - r0) * ncols;              // 1..144
    const unsigned M = 65536u / (unsigned)ncols + 1u;  // magic /ncols, exact k<=159
    const int base0 = (r0 * FW + c0) * FC;

    // offset(k) = ((r0+q)*FW + (c0+cc)) * FC = base0 + q*16384 + cc*256
    auto off = [&](int k) -> int {
        int q = (int)(((unsigned)k * M) >> 16);   // k / ncols
        int cc = k - q * ncols;
        return base0 + (q << 14) + (cc << 8);
    };

    // Pooling: lane owns channels [4*lane, 4*lane+4). Group g takes pixels
    // k = g, g+4, ...; 8 loads in flight (typical cell n<=32 -> one round).
    const float* fbase = features + (size_t)b * FH * FW * FC;
    const float4 negv = {-FLT_MAX, -FLT_MAX, -FLT_MAX, -FLT_MAX};
    float4 m0 = negv, m1 = negv, m2 = negv, m3 = negv;
    float4 m4 = negv, m5 = negv, m6 = negv, m7 = negv;
    int k = group;
    for (; k + 28 < n; k += 32) {
        int o0 = off(k),      o1 = off(k + 4),  o2 = off(k + 8),  o3 = off(k + 12);
        int o4 = off(k + 16), o5 = off(k + 20), o6 = off(k + 24), o7 = off(k + 28);
        float4 v0 = ((const float4*)(fbase + o0))[lane];
        float4 v1 = ((const float4*)(fbase + o1))[lane];
        float4 v2 = ((const float4*)(fbase + o2))[lane];
        float4 v3 = ((const float4*)(fbase + o3))[lane];
        float4 v4 = ((const float4*)(fbase + o4))[lane];
        float4 v5 = ((const float4*)(fbase + o5))[lane];
        float4 v6 = ((const float4*)(fbase + o6))[lane];
        float4 v7 = ((const float4*)(fbase + o7))[lane];
        m0 = max4(m0, v0); m1 = max4(m1, v1);
        m2 = max4(m2, v2); m3 = max4(m3, v3);
        m4 = max4(m4, v4); m5 = max4(m5, v5);
        m6 = max4(m6, v6); m7 = max4(m7, v7);
    }
    for (; k < n; k += 4) {
        float4 v = ((const float4*)(fbase + off(k)))[lane];
        m0 = max4(m0, v);
    }
    sred[group][lane] = max4(max4(max4(m0, m1), max4(m2, m3)),
                             max4(max4(m4, m5), max4(m6, m7)));
    __syncthreads();

    // Final reduce over the 4 groups; coalesced float4 store.
    if (tid < 64) {
        float4 a = max4(max4(sred[0][tid], sred[1][tid]),
                        max4(sred[2][tid], sred[3][tid]));
        float4* ob = (float4*)(out + ((size_t)reg * NCELL + cell) * FC);
        ob[tid] = a;
    }
}

extern "C" void kernel_launch(void* const* d_in, const int* in_sizes, int n_in,
                              void* d_out, int out_size, void* d_ws, size_t ws_size,
                              hipStream_t stream) {
    const float* features = (const float*)d_in[0];  // (4, 64, 64, 256) f32
    const float* roi = (const float*)d_in[1];       // (4, 128, 4) f32
    float* out = (float*)d_out;                     // 294912 + 512 f32 elems
    (void)in_sizes; (void)n_in; (void)out_size; (void)d_ws; (void)ws_size;

    fused_kernel<<<NB * NREG * NCELL, 256, 0, stream>>>(features, roi, out);
}

// Round 4
// 82.444 us; speedup vs baseline: 1.0802x; 1.0802x over previous
//
#include <hip/hip_runtime.h>
#include <float.h>

#define FH 64
#define FW 64
#define FC 256
#define NB 4
#define NR 128
#define NREG 32
#define POOLH 3
#define POOLW 3
#define IOU_THR 0.4f
#define NCELL (POOLH * POOLW)

#define POOLED_ELEMS (NB * NREG * NCELL * FC)

// Python floor-division semantics for /2 on possibly-negative ints:
// arithmetic shift right == floor division by 2 on two's complement.
__device__ inline void fix_axis(int mn, int mx, int ps, int fs, int& omin, int& omax) {
    int pad = ps - (mx - mn);
    bool fix_min = mn < (pad >> 1);
    bool fix_max = (fs - mx) < ((1 + pad) >> 1);
    bool sym = (pad > 0) && !(fix_min || fix_max);
    omin = sym ? (mn - (pad >> 1)) : mn;
    omax = sym ? (mx + ((1 + pad) >> 1)) : mx;
    if ((pad > 0) && fix_min) { omin = 0; omax = ps; }
    if ((pad > 0) && fix_max) { omin = fs - ps; omax = fs; }
}

__device__ inline float4 max4(float4 a, float4 b) {
    float4 o;
    o.x = fmaxf(a.x, b.x); o.y = fmaxf(a.y, b.y);
    o.z = fmaxf(a.z, b.z); o.w = fmaxf(a.w, b.w);
    return o;
}

__device__ inline int imin(int a, int b) { return a < b ? a : b; }

// Broadcast lane `lane`'s 64-bit value to all lanes of the wave (lane uniform).
__device__ inline unsigned long long readlane64(unsigned long long v, int lane) {
    unsigned lo = (unsigned)__builtin_amdgcn_readlane((int)(unsigned)v, lane);
    unsigned hi = (unsigned)__builtin_amdgcn_readlane((int)(unsigned)(v >> 32), lane);
    return ((unsigned long long)hi << 32) | lo;
}

// One block per (region, pool-cell). Redundant bitmask NMS per block, resolve
// via kept-bit scan on wave 0 with register-held rows (readlane fetch), then
// float4 pooling: in-register offsets (magic div) and ALWAYS 8 loads in
// flight via index clamping (duplicate pixels are free under max).
__global__ __launch_bounds__(256) void fused_kernel(
    const float* __restrict__ features,  // (B, H, W, C)
    const float* __restrict__ roi,       // (B, R, 4)
    float* __restrict__ out)             // pooled (B,32,3,3,C) ++ roi_clipped (B,32,4)
{
    // XCD batch-affinity swizzle: consecutive hw block IDs round-robin the 8
    // XCDs (id & 7). Put batch b's 288 blocks on XCD pair {2b, 2b+1} so its
    // 4 MB feature slab stays resident in 8 MB of paired L2.
    const int hwid = blockIdx.x;
    const int b = (hwid >> 1) & 3;
    const int j = (hwid >> 3) * 2 + (hwid & 1);   // 0..287 within batch
    const int r = j / NCELL;                      // region 0..31
    const int cell = j - r * NCELL;               // 0..8
    const int ci = cell / POOLW, cj = cell - ci * POOLW;
    const int reg = b * NREG + r;
    const int tid = threadIdx.x;
    const int group = tid >> 6;                   // 0..3
    const int lane = tid & 63;

    __shared__ float sx1[NR], sy1[NR], sx2[NR], sy2[NR], sarea[NR];
    __shared__ unsigned long long smask[NR][2];
    __shared__ int sbox[4];
    __shared__ float4 sred[4][64];

    // Load this batch's boxes
    if (tid < NR) {
        const float4 bx = *(const float4*)(roi + ((size_t)b * NR + tid) * 4);
        sx1[tid] = bx.x; sy1[tid] = bx.y;
        sx2[tid] = bx.x + bx.z; sy2[tid] = bx.y + bx.w;
        sarea[tid] = bx.z * bx.w;
    }
    __syncthreads();

    // Row-build: p = tid&127 owns row p; half = tid>>7 covers 64 j's.
    // Division-free IoU: inter/(A+B-inter) > t <=> inter > t*(A+B-inter).
    {
        const int p = tid & 127;
        const int half = tid >> 7;
        const int j0 = half << 6;
        const float px1 = sx1[p], py1 = sy1[p], px2 = sx2[p], py2 = sy2[p], pa = sarea[p];
        unsigned long long m = 0ull;
        #pragma unroll 8
        for (int t = 0; t < 64; ++t) {
            const int jj = j0 + t;
            float iw = fmaxf(fminf(px2, sx2[jj]) - fmaxf(px1, sx1[jj]), 0.0f);
            float ih = fmaxf(fminf(py2, sy2[jj]) - fmaxf(py1, sy1[jj]), 0.0f);
            float inter = iw * ih;
            bool sup = (jj > p) && (inter > IOU_THR * (pa + sarea[jj] - inter));
            m |= ((unsigned long long)sup) << t;
        }
        smask[p][half] = m;
    }
    __syncthreads();

    // Resolve on wave 0: scan kept bits (a box still set when reached is
    // final-kept -> enumerate kept in ascending order, stop at 32). Rows are
    // held in wave-0 registers; fetch by readlane (no LDS latency).
    if (tid < 64) {
        const unsigned long long aLo = smask[tid][0];       // row tid, bits [0,64)
        const unsigned long long aHi = smask[tid][1];       // row tid, bits [64,128)
        const unsigned long long bHi = smask[tid + 64][1];  // row tid+64 (low half is 0)

        unsigned long long k1 = ~0ull;   // half-1 survivors under half-0 kept rows
        int cnt = 0, idx = NR - 1;

        unsigned long long cur = ~0ull;  // half-0 candidates
        while (cur && cnt < NREG) {
            int p = __ffsll((unsigned long long)cur) - 1;
            if (cnt == r) idx = p;
            ++cnt;
            int ps = __builtin_amdgcn_readfirstlane(p);
            unsigned long long m0 = readlane64(aLo, ps);
            unsigned long long m1 = readlane64(aHi, ps);
            cur = (cur & (cur - 1)) & ~m0;   // drop p + its suppressions
            k1 &= ~m1;
        }
        cur = k1;
        while (cur && cnt < NREG) {
            int p = __ffsll((unsigned long long)cur) - 1;
            if (cnt == r) idx = 64 + p;
            ++cnt;
            int ps = __builtin_amdgcn_readfirstlane(p);
            unsigned long long m1 = readlane64(bHi, ps);
            cur = (cur & (cur - 1)) & ~m1;
        }

        if (tid == 0) {
            // Clip from LDS: sx2 = x1+w exactly matches reference x+w.
            float x1 = sx1[idx], y1 = sy1[idx], x2f = sx2[idx], y2f = sy2[idx];
            int x_min = (int)fmaxf(0.0f, x1);
            int y_min = (int)fmaxf(0.0f, y1);
            int x_max = (int)fminf((float)FW, x2f);
            int y_max = (int)fminf((float)FH, y2f);
            int xmn, xmx, ymn, ymx;
            fix_axis(x_min, x_max, POOLW, FW, xmn, xmx);
            fix_axis(y_min, y_max, POOLH, FH, ymn, ymx);
            sbox[0] = xmn; sbox[1] = ymn; sbox[2] = xmx - xmn; sbox[3] = ymx - ymn;
            if (cell == 0) {
                float* orc = out + POOLED_ELEMS + ((size_t)reg) * 4;
                orc[0] = (float)xmn;
                orc[1] = (float)ymn;
                orc[2] = (float)(xmx - xmn);
                orc[3] = (float)(ymx - ymn);
            }
        }
    }
    __syncthreads();

    // Cell bounds + in-register offset math (no spix LDS, no extra barrier).
    const int x = sbox[0], y = sbox[1], w = sbox[2], h = sbox[3];
    const int hh = h / POOLH;
    const int ww = w / POOLW;
    const int r0 = y + ci * hh;
    const int r1 = (ci < POOLH - 1) ? (y + (ci + 1) * hh) : (y + h);
    const int c0 = x + cj * ww;
    const int c1 = (cj < POOLW - 1) ? (x + (cj + 1) * ww) : (x + w);
    const int ncols = c1 - c0;                    // 1..12
    const int n = (r1 - r0) * ncols;              // 1..144
    const unsigned M = 65536u / (unsigned)ncols + 1u;  // magic /ncols, exact k<=159
    const int base0 = (r0 * FW + c0) * FC;

    // offset(k) = ((r0+q)*FW + (c0+cc)) * FC = base0 + q*16384 + cc*256
    auto off = [&](int k) -> int {
        int q = (int)(((unsigned)k * M) >> 16);   // k / ncols
        int cc = k - q * ncols;
        return base0 + (q << 14) + (cc << 8);
    };

    // Pooling: lane owns channels [4*lane, 4*lane+4). Group g takes pixels
    // k = g, g+4, ... Indices are CLAMPED to n-1 so all 8 loads always
    // issue in parallel (duplicate pixels are no-ops under max) -> zero
    // serial tail; typical n<=32 is exactly one latency round.
    const float* fbase = features + (size_t)b * FH * FW * FC;
    const float4 negv = {-FLT_MAX, -FLT_MAX, -FLT_MAX, -FLT_MAX};
    float4 m0 = negv, m1 = negv, m2 = negv, m3 = negv;
    float4 m4 = negv, m5 = negv, m6 = negv, m7 = negv;
    const int nm1 = n - 1;
    for (int k = group; k < n; k += 32) {
        int o0 = off(imin(k,      nm1)), o1 = off(imin(k + 4,  nm1));
        int o2 = off(imin(k + 8,  nm1)), o3 = off(imin(k + 12, nm1));
        int o4 = off(imin(k + 16, nm1)), o5 = off(imin(k + 20, nm1));
        int o6 = off(imin(k + 24, nm1)), o7 = off(imin(k + 28, nm1));
        float4 v0 = ((const float4*)(fbase + o0))[lane];
        float4 v1 = ((const float4*)(fbase + o1))[lane];
        float4 v2 = ((const float4*)(fbase + o2))[lane];
        float4 v3 = ((const float4*)(fbase + o3))[lane];
        float4 v4 = ((const float4*)(fbase + o4))[lane];
        float4 v5 = ((const float4*)(fbase + o5))[lane];
        float4 v6 = ((const float4*)(fbase + o6))[lane];
        float4 v7 = ((const float4*)(fbase + o7))[lane];
        m0 = max4(m0, v0); m1 = max4(m1, v1);
        m2 = max4(m2, v2); m3 = max4(m3, v3);
        m4 = max4(m4, v4); m5 = max4(m5, v5);
        m6 = max4(m6, v6); m7 = max4(m7, v7);
    }
    sred[group][lane] = max4(max4(max4(m0, m1), max4(m2, m3)),
                             max4(max4(m4, m5), max4(m6, m7)));
    __syncthreads();

    // Final reduce over the 4 groups; coalesced float4 store.
    if (tid < 64) {
        float4 a = max4(max4(sred[0][tid], sred[1][tid]),
                        max4(sred[2][tid], sred[3][tid]));
        float4* ob = (float4*)(out + ((size_t)reg * NCELL + cell) * FC);
        ob[tid] = a;
    }
}

extern "C" void kernel_launch(void* const* d_in, const int* in_sizes, int n_in,
                              void* d_out, int out_size, void* d_ws, size_t ws_size,
                              hipStream_t stream) {
    const float* features = (const float*)d_in[0];  // (4, 64, 64, 256) f32
    const float* roi = (const float*)d_in[1];       // (4, 128, 4) f32
    float* out = (float*)d_out;                     // 294912 + 512 f32 elems
    (void)in_sizes; (void)n_in; (void)out_size; (void)d_ws; (void)ws_size;

    fused_kernel<<<NB * NREG * NCELL, 256, 0, stream>>>(features, roi, out);
}

// Round 5
// 81.783 us; speedup vs baseline: 1.0889x; 1.0081x over previous
//
#include <hip/hip_runtime.h>
#include <float.h>

#define FH 64
#define FW 64
#define FC 256
#define NB 4
#define NR 128
#define NREG 32
#define POOLH 3
#define POOLW 3
#define IOU_THR 0.4f
#define NCELL (POOLH * POOLW)
#define MAXPIX 160   // max cell pixels: last band <= 12 -> 12*12=144, padded

#define POOLED_ELEMS (NB * NREG * NCELL * FC)

// Python floor-division semantics for /2 on possibly-negative ints:
// arithmetic shift right == floor division by 2 on two's complement.
__device__ inline void fix_axis(int mn, int mx, int ps, int fs, int& omin, int& omax) {
    int pad = ps - (mx - mn);
    bool fix_min = mn < (pad >> 1);
    bool fix_max = (fs - mx) < ((1 + pad) >> 1);
    bool sym = (pad > 0) && !(fix_min || fix_max);
    omin = sym ? (mn - (pad >> 1)) : mn;
    omax = sym ? (mx + ((1 + pad) >> 1)) : mx;
    if ((pad > 0) && fix_min) { omin = 0; omax = ps; }
    if ((pad > 0) && fix_max) { omin = fs - ps; omax = fs; }
}

__device__ inline float4 max4(float4 a, float4 b) {
    float4 o;
    o.x = fmaxf(a.x, b.x); o.y = fmaxf(a.y, b.y);
    o.z = fmaxf(a.z, b.z); o.w = fmaxf(a.w, b.w);
    return o;
}

__device__ inline int imin(int a, int b) { return a < b ? a : b; }

// Broadcast lane `lane`'s 64-bit value to all lanes of the wave (lane uniform).
__device__ inline unsigned long long readlane64(unsigned long long v, int lane) {
    unsigned lo = (unsigned)__builtin_amdgcn_readlane((int)(unsigned)v, lane);
    unsigned hi = (unsigned)__builtin_amdgcn_readlane((int)(unsigned)(v >> 32), lane);
    return ((unsigned long long)hi << 32) | lo;
}

// One block per (region, pool-cell). Redundant bitmask NMS per block, resolve
// via kept-bit scan on wave 0 with register-held rows (readlane fetch), then
// float4 pooling from the spix LDS table with ALWAYS 8 loads in flight via
// index clamping (duplicate pixels are no-ops under max) -> zero serial tail.
__global__ __launch_bounds__(256) void fused_kernel(
    const float* __restrict__ features,  // (B, H, W, C)
    const float* __restrict__ roi,       // (B, R, 4)
    float* __restrict__ out)             // pooled (B,32,3,3,C) ++ roi_clipped (B,32,4)
{
    // XCD batch-affinity swizzle: consecutive hw block IDs round-robin the 8
    // XCDs (id & 7). Put batch b's 288 blocks on XCD pair {2b, 2b+1} so its
    // 4 MB feature slab stays resident in 8 MB of paired L2.
    const int hwid = blockIdx.x;
    const int b = (hwid >> 1) & 3;
    const int j = (hwid >> 3) * 2 + (hwid & 1);   // 0..287 within batch
    const int r = j / NCELL;                      // region 0..31
    const int cell = j - r * NCELL;               // 0..8
    const int ci = cell / POOLW, cj = cell - ci * POOLW;
    const int reg = b * NREG + r;
    const int tid = threadIdx.x;
    const int group = tid >> 6;                   // 0..3
    const int lane = tid & 63;

    __shared__ float sx1[NR], sy1[NR], sx2[NR], sy2[NR], sarea[NR];
    __shared__ unsigned long long smask[NR][2];
    __shared__ int sbox[4];
    __shared__ int spix[MAXPIX];
    __shared__ float4 sred[4][64];

    // Load this batch's boxes
    if (tid < NR) {
        const float4 bx = *(const float4*)(roi + ((size_t)b * NR + tid) * 4);
        sx1[tid] = bx.x; sy1[tid] = bx.y;
        sx2[tid] = bx.x + bx.z; sy2[tid] = bx.y + bx.w;
        sarea[tid] = bx.z * bx.w;
    }
    __syncthreads();

    // Row-build: p = tid&127 owns row p; half = tid>>7 covers 64 j's.
    // Division-free IoU: inter/(A+B-inter) > t <=> inter > t*(A+B-inter).
    {
        const int p = tid & 127;
        const int half = tid >> 7;
        const int j0 = half << 6;
        const float px1 = sx1[p], py1 = sy1[p], px2 = sx2[p], py2 = sy2[p], pa = sarea[p];
        unsigned long long m = 0ull;
        #pragma unroll 8
        for (int t = 0; t < 64; ++t) {
            const int jj = j0 + t;
            float iw = fmaxf(fminf(px2, sx2[jj]) - fmaxf(px1, sx1[jj]), 0.0f);
            float ih = fmaxf(fminf(py2, sy2[jj]) - fmaxf(py1, sy1[jj]), 0.0f);
            float inter = iw * ih;
            bool sup = (jj > p) && (inter > IOU_THR * (pa + sarea[jj] - inter));
            m |= ((unsigned long long)sup) << t;
        }
        smask[p][half] = m;
    }
    __syncthreads();

    // Resolve on wave 0: scan kept bits (a box still set when reached is
    // final-kept -> enumerate kept in ascending order, stop at 32). Rows are
    // held in wave-0 registers; fetch by readlane (no LDS latency).
    if (tid < 64) {
        const unsigned long long aLo = smask[tid][0];       // row tid, bits [0,64)
        const unsigned long long aHi = smask[tid][1];       // row tid, bits [64,128)
        const unsigned long long bHi = smask[tid + 64][1];  // row tid+64 (low half is 0)

        unsigned long long k1 = ~0ull;   // half-1 survivors under half-0 kept rows
        int cnt = 0, idx = NR - 1;

        unsigned long long cur = ~0ull;  // half-0 candidates
        while (cur && cnt < NREG) {
            int p = __ffsll((unsigned long long)cur) - 1;
            if (cnt == r) idx = p;
            ++cnt;
            int ps = __builtin_amdgcn_readfirstlane(p);
            unsigned long long m0 = readlane64(aLo, ps);
            unsigned long long m1 = readlane64(aHi, ps);
            cur = (cur & (cur - 1)) & ~m0;   // drop p + its suppressions
            k1 &= ~m1;
        }
        cur = k1;
        while (cur && cnt < NREG) {
            int p = __ffsll((unsigned long long)cur) - 1;
            if (cnt == r) idx = 64 + p;
            ++cnt;
            int ps = __builtin_amdgcn_readfirstlane(p);
            unsigned long long m1 = readlane64(bHi, ps);
            cur = (cur & (cur - 1)) & ~m1;
        }

        if (tid == 0) {
            // Clip from LDS: sx2 = x1+w exactly matches reference x+w.
            float x1 = sx1[idx], y1 = sy1[idx], x2f = sx2[idx], y2f = sy2[idx];
            int x_min = (int)fmaxf(0.0f, x1);
            int y_min = (int)fmaxf(0.0f, y1);
            int x_max = (int)fminf((float)FW, x2f);
            int y_max = (int)fminf((float)FH, y2f);
            int xmn, xmx, ymn, ymx;
            fix_axis(x_min, x_max, POOLW, FW, xmn, xmx);
            fix_axis(y_min, y_max, POOLH, FH, ymn, ymx);
            sbox[0] = xmn; sbox[1] = ymn; sbox[2] = xmx - xmn; sbox[3] = ymx - ymn;
            if (cell == 0) {
                float* orc = out + POOLED_ELEMS + ((size_t)reg) * 4;
                orc[0] = (float)xmn;
                orc[1] = (float)ymn;
                orc[2] = (float)(xmx - xmn);
                orc[3] = (float)(ymx - ymn);
            }
        }
    }
    __syncthreads();

    // Cell bounds
    const int x = sbox[0], y = sbox[1], w = sbox[2], h = sbox[3];
    const int hh = h / POOLH;
    const int ww = w / POOLW;
    const int r0 = y + ci * hh;
    const int r1 = (ci < POOLH - 1) ? (y + (ci + 1) * hh) : (y + h);
    const int c0 = x + cj * ww;
    const int c1 = (cj < POOLW - 1) ? (x + (cj + 1) * ww) : (x + w);
    const int ncols = c1 - c0;
    const int n = (r1 - r0) * ncols;          // 1..144

    // Pixel offsets (channel-independent), index math amortized across threads
    if (tid < n) {
        int q = tid / ncols;
        int cc = tid - q * ncols;
        spix[tid] = ((r0 + q) * FW + (c0 + cc)) * FC;
    }
    __syncthreads();

    // Pooling: lane owns channels [4*lane, 4*lane+4). Group g takes pixels
    // k = g, g+4, ... Indices CLAMPED to n-1 so all 8 loads always issue in
    // parallel (duplicates are no-ops under max) -> zero serial tail; the
    // typical n<=32 cell completes its gathers in exactly one latency round.
    const float* fbase = features + (size_t)b * FH * FW * FC;
    const float4 negv = {-FLT_MAX, -FLT_MAX, -FLT_MAX, -FLT_MAX};
    float4 m0 = negv, m1 = negv, m2 = negv, m3 = negv;
    float4 m4 = negv, m5 = negv, m6 = negv, m7 = negv;
    const int nm1 = n - 1;
    for (int k = group; k < n; k += 32) {
        int o0 = spix[imin(k,      nm1)], o1 = spix[imin(k + 4,  nm1)];
        int o2 = spix[imin(k + 8,  nm1)], o3 = spix[imin(k + 12, nm1)];
        int o4 = spix[imin(k + 16, nm1)], o5 = spix[imin(k + 20, nm1)];
        int o6 = spix[imin(k + 24, nm1)], o7 = spix[imin(k + 28, nm1)];
        float4 v0 = ((const float4*)(fbase + o0))[lane];
        float4 v1 = ((const float4*)(fbase + o1))[lane];
        float4 v2 = ((const float4*)(fbase + o2))[lane];
        float4 v3 = ((const float4*)(fbase + o3))[lane];
        float4 v4 = ((const float4*)(fbase + o4))[lane];
        float4 v5 = ((const float4*)(fbase + o5))[lane];
        float4 v6 = ((const float4*)(fbase + o6))[lane];
        float4 v7 = ((const float4*)(fbase + o7))[lane];
        m0 = max4(m0, v0); m1 = max4(m1, v1);
        m2 = max4(m2, v2); m3 = max4(m3, v3);
        m4 = max4(m4, v4); m5 = max4(m5, v5);
        m6 = max4(m6, v6); m7 = max4(m7, v7);
    }
    sred[group][lane] = max4(max4(max4(m0, m1), max4(m2, m3)),
                             max4(max4(m4, m5), max4(m6, m7)));
    __syncthreads();

    // Final reduce over the 4 groups; coalesced float4 store.
    if (tid < 64) {
        float4 a = max4(max4(sred[0][tid], sred[1][tid]),
                        max4(sred[2][tid], sred[3][tid]));
        float4* ob = (float4*)(out + ((size_t)reg * NCELL + cell) * FC);
        ob[tid] = a;
    }
}

extern "C" void kernel_launch(void* const* d_in, const int* in_sizes, int n_in,
                              void* d_out, int out_size, void* d_ws, size_t ws_size,
                              hipStream_t stream) {
    const float* features = (const float*)d_in[0];  // (4, 64, 64, 256) f32
    const float* roi = (const float*)d_in[1];       // (4, 128, 4) f32
    float* out = (float*)d_out;                     // 294912 + 512 f32 elems
    (void)in_sizes; (void)n_in; (void)out_size; (void)d_ws; (void)ws_size;

    fused_kernel<<<NB * NREG * NCELL, 256, 0, stream>>>(features, roi, out);
}

// Round 6
// 80.800 us; speedup vs baseline: 1.1022x; 1.0122x over previous
//
#include <hip/hip_runtime.h>
#include <float.h>

#define FH 64
#define FW 64
#define FC 256
#define NB 4
#define NR 128
#define NREG 32
#define POOLH 3
#define POOLW 3
#define IOU_THR 0.4f
#define NCELL (POOLH * POOLW)
#define MAXPIX 160   // max cell pixels: last band <= 12 -> 12*12=144, padded

#define POOLED_ELEMS (NB * NREG * NCELL * FC)

// Python floor-division semantics for /2 on possibly-negative ints:
// arithmetic shift right == floor division by 2 on two's complement.
__device__ inline void fix_axis(int mn, int mx, int ps, int fs, int& omin, int& omax) {
    int pad = ps - (mx - mn);
    bool fix_min = mn < (pad >> 1);
    bool fix_max = (fs - mx) < ((1 + pad) >> 1);
    bool sym = (pad > 0) && !(fix_min || fix_max);
    omin = sym ? (mn - (pad >> 1)) : mn;
    omax = sym ? (mx + ((1 + pad) >> 1)) : mx;
    if ((pad > 0) && fix_min) { omin = 0; omax = ps; }
    if ((pad > 0) && fix_max) { omin = fs - ps; omax = fs; }
}

__device__ inline float4 max4(float4 a, float4 b) {
    float4 o;
    o.x = fmaxf(a.x, b.x); o.y = fmaxf(a.y, b.y);
    o.z = fmaxf(a.z, b.z); o.w = fmaxf(a.w, b.w);
    return o;
}

// Broadcast lane `lane`'s 64-bit value to all lanes of the wave (lane uniform).
__device__ inline unsigned long long readlane64(unsigned long long v, int lane) {
    unsigned lo = (unsigned)__builtin_amdgcn_readlane((int)(unsigned)v, lane);
    unsigned hi = (unsigned)__builtin_amdgcn_readlane((int)(unsigned)(v >> 32), lane);
    return ((unsigned long long)hi << 32) | lo;
}

// One block per (region, pool-cell). Redundant bitmask NMS per block, resolve
// via kept-bit scan on wave 0 with register-held rows (readlane fetch), then
// float4 pooling with 4-way pixel split + 4 loads in flight.
__global__ __launch_bounds__(256) void fused_kernel(
    const float* __restrict__ features,  // (B, H, W, C)
    const float* __restrict__ roi,       // (B, R, 4)
    float* __restrict__ out)             // pooled (B,32,3,3,C) ++ roi_clipped (B,32,4)
{
    // XCD batch-affinity swizzle: consecutive hw block IDs round-robin the 8
    // XCDs (id & 7). Put batch b's 288 blocks on XCD pair {2b, 2b+1} so its
    // 4 MB feature slab stays resident in 8 MB of paired L2.
    const int hwid = blockIdx.x;
    const int b = (hwid >> 1) & 3;
    const int j = (hwid >> 3) * 2 + (hwid & 1);   // 0..287 within batch
    const int r = j / NCELL;                      // region 0..31
    const int cell = j - r * NCELL;               // 0..8
    const int ci = cell / POOLW, cj = cell - ci * POOLW;
    const int reg = b * NREG + r;
    const int tid = threadIdx.x;
    const int group = tid >> 6;                   // 0..3
    const int lane = tid & 63;

    __shared__ float sx1[NR], sy1[NR], sx2[NR], sy2[NR], sarea[NR];
    __shared__ unsigned long long smask[NR][2];
    __shared__ int sbox[4];
    __shared__ int spix[MAXPIX];
    __shared__ float4 sred[4][64];

    // Load this batch's boxes
    if (tid < NR) {
        const float4 bx = *(const float4*)(roi + ((size_t)b * NR + tid) * 4);
        sx1[tid] = bx.x; sy1[tid] = bx.y;
        sx2[tid] = bx.x + bx.z; sy2[tid] = bx.y + bx.w;
        sarea[tid] = bx.z * bx.w;
    }
    __syncthreads();

    // Row-build: p = tid&127 owns row p; half = tid>>7 covers 64 j's.
    // Division-free IoU: inter/(A+B-inter) > t <=> inter > t*(A+B-inter).
    {
        const int p = tid & 127;
        const int half = tid >> 7;
        const int j0 = half << 6;
        const float px1 = sx1[p], py1 = sy1[p], px2 = sx2[p], py2 = sy2[p], pa = sarea[p];
        unsigned long long m = 0ull;
        #pragma unroll 8
        for (int t = 0; t < 64; ++t) {
            const int jj = j0 + t;
            float iw = fmaxf(fminf(px2, sx2[jj]) - fmaxf(px1, sx1[jj]), 0.0f);
            float ih = fmaxf(fminf(py2, sy2[jj]) - fmaxf(py1, sy1[jj]), 0.0f);
            float inter = iw * ih;
            bool sup = (jj > p) && (inter > IOU_THR * (pa + sarea[jj] - inter));
            m |= ((unsigned long long)sup) << t;
        }
        smask[p][half] = m;
    }
    __syncthreads();

    // Resolve on wave 0: scan kept bits (a box still set when reached is
    // final-kept -> enumerate kept in ascending order, stop at 32). Rows are
    // held in wave-0 registers; fetch by readlane (no LDS latency).
    if (tid < 64) {
        const unsigned long long aLo = smask[tid][0];       // row tid, bits [0,64)
        const unsigned long long aHi = smask[tid][1];       // row tid, bits [64,128)
        const unsigned long long bHi = smask[tid + 64][1];  // row tid+64 (low half is 0)

        unsigned long long k1 = ~0ull;   // half-1 survivors under half-0 kept rows
        int cnt = 0, idx = NR - 1;

        unsigned long long cur = ~0ull;  // half-0 candidates
        while (cur && cnt < NREG) {
            int p = __ffsll((unsigned long long)cur) - 1;
            if (cnt == r) idx = p;
            ++cnt;
            int ps = __builtin_amdgcn_readfirstlane(p);
            unsigned long long m0 = readlane64(aLo, ps);
            unsigned long long m1 = readlane64(aHi, ps);
            cur = (cur & (cur - 1)) & ~m0;   // drop p + its suppressions
            k1 &= ~m1;
        }
        cur = k1;
        while (cur && cnt < NREG) {
            int p = __ffsll((unsigned long long)cur) - 1;
            if (cnt == r) idx = 64 + p;
            ++cnt;
            int ps = __builtin_amdgcn_readfirstlane(p);
            unsigned long long m1 = readlane64(bHi, ps);
            cur = (cur & (cur - 1)) & ~m1;
        }

        if (tid == 0) {
            // Clip from LDS: sx2 = x1+w exactly matches reference x+w.
            float x1 = sx1[idx], y1 = sy1[idx], x2f = sx2[idx], y2f = sy2[idx];
            int x_min = (int)fmaxf(0.0f, x1);
            int y_min = (int)fmaxf(0.0f, y1);
            int x_max = (int)fminf((float)FW, x2f);
            int y_max = (int)fminf((float)FH, y2f);
            int xmn, xmx, ymn, ymx;
            fix_axis(x_min, x_max, POOLW, FW, xmn, xmx);
            fix_axis(y_min, y_max, POOLH, FH, ymn, ymx);
            sbox[0] = xmn; sbox[1] = ymn; sbox[2] = xmx - xmn; sbox[3] = ymx - ymn;
            if (cell == 0) {
                float* orc = out + POOLED_ELEMS + ((size_t)reg) * 4;
                orc[0] = (float)xmn;
                orc[1] = (float)ymn;
                orc[2] = (float)(xmx - xmn);
                orc[3] = (float)(ymx - ymn);
            }
        }
    }
    __syncthreads();

    // Cell bounds
    const int x = sbox[0], y = sbox[1], w = sbox[2], h = sbox[3];
    const int hh = h / POOLH;
    const int ww = w / POOLW;
    const int r0 = y + ci * hh;
    const int r1 = (ci < POOLH - 1) ? (y + (ci + 1) * hh) : (y + h);
    const int c0 = x + cj * ww;
    const int c1 = (cj < POOLW - 1) ? (x + (cj + 1) * ww) : (x + w);
    const int ncols = c1 - c0;
    const int n = (r1 - r0) * ncols;          // 1..144

    // Pixel offsets (channel-independent)
    if (tid < n) {
        int q = tid / ncols;
        int cc = tid - q * ncols;
        spix[tid] = ((r0 + q) * FW + (c0 + cc)) * FC;
    }
    __syncthreads();

    // Pooling: lane owns channels [4*lane, 4*lane+4). Group g takes pixels
    // k = g, g+4, ...; batches of 4 loads in flight.
    const float* fbase = features + (size_t)b * FH * FW * FC;
    const float4 negv = {-FLT_MAX, -FLT_MAX, -FLT_MAX, -FLT_MAX};
    float4 m0 = negv, m1 = negv, m2 = negv, m3 = negv;
    int k = group;
    for (; k + 12 < n; k += 16) {
        int o0 = spix[k], o1 = spix[k + 4], o2 = spix[k + 8], o3 = spix[k + 12];
        float4 v0 = ((const float4*)(fbase + o0))[lane];
        float4 v1 = ((const float4*)(fbase + o1))[lane];
        float4 v2 = ((const float4*)(fbase + o2))[lane];
        float4 v3 = ((const float4*)(fbase + o3))[lane];
        m0 = max4(m0, v0); m1 = max4(m1, v1);
        m2 = max4(m2, v2); m3 = max4(m3, v3);
    }
    for (; k < n; k += 4) {
        float4 v = ((const float4*)(fbase + spix[k]))[lane];
        m0 = max4(m0, v);
    }
    sred[group][lane] = max4(max4(m0, m1), max4(m2, m3));
    __syncthreads();

    // Final reduce over the 4 groups; coalesced float4 store.
    if (tid < 64) {
        float4 a = max4(max4(sred[0][tid], sred[1][tid]),
                        max4(sred[2][tid], sred[3][tid]));
        float4* ob = (float4*)(out + ((size_t)reg * NCELL + cell) * FC);
        ob[tid] = a;
    }
}

extern "C" void kernel_launch(void* const* d_in, const int* in_sizes, int n_in,
                              void* d_out, int out_size, void* d_ws, size_t ws_size,
                              hipStream_t stream) {
    const float* features = (const float*)d_in[0];  // (4, 64, 64, 256) f32
    const float* roi = (const float*)d_in[1];       // (4, 128, 4) f32
    float* out = (float*)d_out;                     // 294912 + 512 f32 elems
    (void)in_sizes; (void)n_in; (void)out_size; (void)d_ws; (void)ws_size;

    fused_kernel<<<NB * NREG * NCELL, 256, 0, stream>>>(features, roi, out);
}